// Round 3
// baseline (272.069 us; speedup 1.0000x reference)
//
#include <hip/hip_runtime.h>

// Attention B=4,H=16,S=2048,D=64. fp32 in/out, mask int32 (nonzero=masked).
// Round 10: register-pressure diet (kill AGPR<->VGPR shuttling).
//  - sequential sub-tile chains: QK0->SM0->QK1->SM1->PV0->PV1; sc0 dies into
//    packed bf16 frags before sc1 lives -> peak unified regs ~115 < 128 cap
//  - P-frags built directly as bf16x8 pairs (no union copy step)
//  - mask words for the two sub-tiles adjacent in memory: one dwordx2/group
// MFMA 32x32x16 layouts (verified m74/m101):
//   A: lane holds A[m=lane&31][k=(lane>>5)*8+j]
//   B: lane holds B[k=(lane>>5)*8+j][n=lane&31]
//   C/D: lane holds D[row=(reg&3)+8*(reg>>2)+4*(lane>>5)][col=lane&31]

#define SEQ 2048
#define DIM 64
#define NBH 64
#define LOG2E 1.44269504088896340736f
#define SCL (0.125f * LOG2E)
#define NEG_SCALED -1.25e8f

typedef short bf16x8 __attribute__((ext_vector_type(8)));
typedef float f32x4 __attribute__((ext_vector_type(4)));
typedef float f32x16 __attribute__((ext_vector_type(16)));

static __device__ __forceinline__ unsigned short f2bf(float f) {
    unsigned int u = __float_as_uint(f);
    u += 0x7fffu + ((u >> 16) & 1u);   // RNE
    return (unsigned short)(u >> 16);
}

// async global->LDS, 16B per lane; LDS dest = wave-uniform base + lane*16
#define GLD16(gp, lp) __builtin_amdgcn_global_load_lds( \
    (const __attribute__((address_space(1))) unsigned int*)(gp), \
    (__attribute__((address_space(3))) unsigned int*)(lp), 16, 0, 0)

// ---------------- fused prepass ----------------
// blocks [0,1024): mask; [1024,5120): K cvt; [5120,7168): V^T (tau key order)
__global__ __launch_bounds__(256)
void prep_all_kernel(const float* __restrict__ K, const float* __restrict__ V,
                     const int* __restrict__ M,
                     unsigned short* __restrict__ Kb, unsigned short* __restrict__ Vt,
                     unsigned int* __restrict__ Mpt) {
    const int x = blockIdx.x;
    const int t = threadIdx.x;
    if (x < 1024) {
        // mask: int32 -> 1 bit/key, transposed+paired: Mpt[b][g64][q][e],
        // e = low/high 32-key half of the 64-key group (adjacent dwords).
        __shared__ unsigned int Wt[64][8];
        const int m  = x;                      // 0..1023
        const int b  = m >> 8;
        const int q0 = ((m >> 3) & 31) * 64;
        const int k0 = (m & 7) * 256;
        const int w  = t >> 6, l = t & 63;
        #pragma unroll 4
        for (int row = 0; row < 16; ++row) {
            const int q = q0 + w * 16 + row;
            int4 v4 = *(const int4*)(M + ((size_t)b * SEQ + q) * SEQ + k0 + l * 4);
            unsigned int nib = (unsigned int)(v4.x != 0) | ((unsigned int)(v4.y != 0) << 1)
                             | ((unsigned int)(v4.z != 0) << 2) | ((unsigned int)(v4.w != 0) << 3);
            unsigned int v = nib << (4 * (l & 7));
            v |= __shfl_xor(v, 1);
            v |= __shfl_xor(v, 2);
            v |= __shfl_xor(v, 4);
            if ((l & 7) == 0) Wt[w * 16 + row][l >> 3] = v;
        }
        __syncthreads();
        {
            const int q = t & 63, g0 = t >> 6;
            #pragma unroll
            for (int gg = 0; gg < 2; ++gg) {
                const int g = g0 + gg * 4;           // local 32-key tile 0..7
                const int G = (k0 >> 5) + g;         // global 32-key tile 0..63
                Mpt[(((size_t)b * 32 + (G >> 1)) * SEQ + q0 + q) * 2 + (G & 1)] = Wt[q][g];
            }
        }
    } else if (x < 5120) {
        // K: fp32 -> bf16 row-major, 8 els/thread
        size_t i0 = ((size_t)(x - 1024) * 256 + t) * 8;
        float4 a = *(const float4*)(K + i0);
        float4 b = *(const float4*)(K + i0 + 4);
        union { uint4 u; unsigned short s[8]; } w;
        w.s[0] = f2bf(a.x); w.s[1] = f2bf(a.y); w.s[2] = f2bf(a.z); w.s[3] = f2bf(a.w);
        w.s[4] = f2bf(b.x); w.s[5] = f2bf(b.y); w.s[6] = f2bf(b.z); w.s[7] = f2bf(b.w);
        *(uint4*)(Kb + i0) = w.u;
    } else {
        // V: fp32 -> bf16 transposed Vt[bh][d][u] with u = tau(key):
        // position u holds physical key swap23(u) (tau is self-inverse).
        __shared__ __align__(16) unsigned short T[64 * 64];
        const int vb = x - 5120;
        const int bh = vb >> 5;
        const int k0 = (vb & 31) * 64;
        {
            const float* Vb = V + ((size_t)bh * SEQ + k0) * DIM;
            #pragma unroll
            for (int j = 0; j < 4; ++j) {
                const int fi = (j * 256 + t) * 4;      // float idx in 64x64 tile
                const int kk = fi >> 6;                // physical key (local)
                const int d0 = fi & 63;                // multiple of 4
                float4 f = *(const float4*)(Vb + fi);
                const int u  = (kk & ~12) | ((kk & 4) << 1) | ((kk & 8) >> 1); // swap23
                const int cs = (d0 >> 4) ^ ((u >> 3) & 3);
                union { uint2 q; unsigned short s[4]; } w4;
                w4.s[0] = f2bf(f.x); w4.s[1] = f2bf(f.y);
                w4.s[2] = f2bf(f.z); w4.s[3] = f2bf(f.w);
                *(uint2*)&T[u * 64 + cs * 16 + (d0 & 15)] = w4.q;
            }
        }
        __syncthreads();
        {
            const int kc = t & 7;
            const int dp = t >> 3;
            const int ch = (dp >> 3) ^ (kc & 3);
            const unsigned int* T32 = (const unsigned int*)T;
            union { uint4 u; unsigned short s[8]; } o0, o1;
            #pragma unroll
            for (int i = 0; i < 8; ++i) {
                unsigned int v = T32[(8 * kc + i) * 32 + ch * 8 + (dp & 7)];
                o0.s[i] = (unsigned short)v;
                o1.s[i] = (unsigned short)(v >> 16);
            }
            unsigned short* op = Vt + ((size_t)bh * DIM + 2 * dp) * SEQ + k0 + 8 * kc;
            *(uint4*)op         = o0.u;
            *(uint4*)(op + SEQ) = o1.u;
        }
    }
}

// ---------------- main ----------------

// QK^T (S^T) for one 32-key sub-tile: C-init from mask bits, 4 mfmas over d.
#define TILE_QK(sc, Ktb, mqv)                                                   \
    {                                                                           \
        _Pragma("unroll")                                                       \
        for (int r = 0; r < 16; ++r) {                                          \
            const int s_ = (r & 3) + 8 * (r >> 2);                              \
            sc[r] = __int_as_float(__builtin_amdgcn_sbfe(mqv, s_, 1) & 0xC2C80000u); \
        }                                                                       \
        __builtin_amdgcn_s_setprio(1);                                          \
        _Pragma("unroll")                                                       \
        for (int dc = 0; dc < 4; ++dc) {                                        \
            const int pos = (dc * 2 + h) ^ (q32 & 7);                           \
            bf16x8 kf = *(const bf16x8*)((Ktb) + q32 * 64 + pos * 8);           \
            sc = __builtin_amdgcn_mfma_f32_32x32x16_bf16(kf, qf[dc], sc, 0, 0, 0); \
        }                                                                       \
        __builtin_amdgcn_s_setprio(0);                                          \
    }

// softmax finish (fixed-max; masked scores were init'd to -100): sc -> packed
// bf16 P-frags (pa = keys 0..15 group, pb = 16..31 group) + lsum chains.
// sc dies here -> register pressure stays under the 128-reg unified cap.
#define TILE_SM(sc, pa, pb)                                                     \
    {                                                                           \
        float pv_[16];                                                          \
        _Pragma("unroll")                                                       \
        for (int r = 0; r < 16; ++r) pv_[r] = __builtin_amdgcn_exp2f(sc[r]);    \
        _Pragma("unroll")                                                       \
        for (int r = 0; r < 16; r += 4) {                                       \
            ls0 += pv_[r + 0]; ls1 += pv_[r + 1];                               \
            ls2 += pv_[r + 2]; ls3 += pv_[r + 3];                               \
        }                                                                       \
        _Pragma("unroll")                                                       \
        for (int m = 0; m < 4; ++m) {                                           \
            asm("v_cvt_pk_bf16_f32 %0, %1, %2"                                  \
                : "=v"(pa.u[m]) : "v"(pv_[2 * m]), "v"(pv_[2 * m + 1]));        \
            asm("v_cvt_pk_bf16_f32 %0, %1, %2"                                  \
                : "=v"(pb.u[m]) : "v"(pv_[8 + 2 * m]), "v"(pv_[9 + 2 * m]));    \
        }                                                                       \
    }

// PV for one sub-tile: O^T += V^T(A) . P^T(B); frags are in-lane (tau order).
#define TILE_PV(pa, pb, Vsb)                                                    \
    {                                                                           \
        __builtin_amdgcn_s_setprio(1);                                          \
        _Pragma("unroll")                                                       \
        for (int dh = 0; dh < 2; ++dh) {                                        \
            const int d = dh * 32 + q32;                                        \
            const int pos0 = (0 * 2 + h) ^ ((q32 >> 1) & 3);                    \
            const int pos1 = (1 * 2 + h) ^ ((q32 >> 1) & 3);                    \
            bf16x8 vf0 = *(const bf16x8*)((Vsb) + d * 32 + pos0 * 8);           \
            acc[dh] = __builtin_amdgcn_mfma_f32_32x32x16_bf16(vf0, pa.v, acc[dh], 0, 0, 0); \
            bf16x8 vf1 = *(const bf16x8*)((Vsb) + d * 32 + pos1 * 8);           \
            acc[dh] = __builtin_amdgcn_mfma_f32_32x32x16_bf16(vf1, pb.v, acc[dh], 0, 0, 0); \
        }                                                                       \
        __builtin_amdgcn_s_setprio(0);                                          \
    }

__global__ __launch_bounds__(256, 4)
void attn_main_kernel(const float* __restrict__ Q,
                      const unsigned short* __restrict__ Kb,
                      const unsigned short* __restrict__ Vt,
                      const unsigned int* __restrict__ Mpt,
                      float* __restrict__ O)
{
    // XCD swizzle: n = linear block id (x fastest). XCD ~ n%8 (round-robin).
    // bh = ((n&7)<<3) | (n>>7): each XCD owns 8 consecutive bh (a single b),
    // all 16 q-blocks of each bh -> K/V/mask tiles stay L2-resident.
    const int n    = blockIdx.y * gridDim.x + blockIdx.x;   // [0,1024)
    const int bh   = ((n & 7) << 3) | (n >> 7);
    const int q0   = ((n >> 3) & 15) * 128;
    const int b    = bh >> 4;
    const int tid  = threadIdx.x;
    const int wave = tid >> 6;
    const int lane = tid & 63;
    const int h    = lane >> 5;    // k-half for 32x32 frags
    const int q32  = lane & 31;
    const int sh4  = 4 * h;

    // [buf][subtile][...]: K [key][d] chunk-swizzled, V [d][u] chunk-swizzled
    __shared__ __align__(16) unsigned short Kt[2][2][32 * 64];
    __shared__ __align__(16) unsigned short Vs[2][2][64 * 32];

    const unsigned short* Kbh = Kb + (size_t)bh * SEQ * DIM;
    const unsigned short* Vbh = Vt + (size_t)bh * SEQ * DIM;

    // ---- Q B-frags (Q^T): lane holds Q[q=q32][d = dc*16 + h*8 + j], scale folded ----
    bf16x8 qf[4];
    {
        const float* qp = Q + ((size_t)bh * SEQ + q0 + wave * 32 + q32) * DIM + h * 8;
        #pragma unroll
        for (int dc = 0; dc < 4; ++dc) {
            float4 xx = *(const float4*)(qp + dc * 16);
            float4 yy = *(const float4*)(qp + dc * 16 + 4);
            qf[dc][0] = (short)f2bf(xx.x * SCL); qf[dc][1] = (short)f2bf(xx.y * SCL);
            qf[dc][2] = (short)f2bf(xx.z * SCL); qf[dc][3] = (short)f2bf(xx.w * SCL);
            qf[dc][4] = (short)f2bf(yy.x * SCL); qf[dc][5] = (short)f2bf(yy.y * SCL);
            qf[dc][6] = (short)f2bf(yy.z * SCL); qf[dc][7] = (short)f2bf(yy.w * SCL);
        }
    }

    // ---- DMA lane mapping (source-address XOR swizzle) ----
    const int kkey  = wave * 8 + (lane >> 3);
    const int kclog = (lane & 7) ^ (lane >> 3);
    const unsigned short* kg = Kbh + (size_t)kkey * DIM + kclog * 8;
    const int vd    = wave * 16 + (lane >> 2);
    const int vclog = (lane & 3) ^ ((lane >> 3) & 3);   // swizzle basis (d>>1)&3
    const unsigned short* vg = Vbh + (size_t)vd * SEQ + vclog * 8;
    unsigned short* kl0 = &Kt[0][0][wave * 512];
    unsigned short* vl0 = &Vs[0][0][wave * 512];

    // paired transposed mask: one dwordx2 per lane per 64-key group
    const unsigned int* mp = Mpt + ((size_t)b * 32 * SEQ + q0 + wave * 32 + q32) * 2;

    f32x16 acc[2];
    #pragma unroll
    for (int i = 0; i < 16; ++i) { acc[0][i] = 0.f; acc[1][i] = 0.f; }
    float ls0 = 0.f, ls1 = 0.f, ls2 = 0.f, ls3 = 0.f;

    // prologue: stage key-group 0 (both sub-tiles)
    GLD16(kg,                     kl0);
    GLD16(kg + (size_t)32 * DIM,  kl0 + 2048);
    GLD16(vg,                     vl0);
    GLD16(vg + 32,                vl0 + 2048);
    uint2 mwp = *(const uint2*)mp;

    #pragma unroll 2
    for (int g = 0; g < SEQ / 64; ++g) {
        __syncthreads();   // drains vmcnt -> buf (g&1) ready for all waves;
                           // prefetch below is 1 group old at next drain

        uint2 mwpn = {0u, 0u};
        if (g + 1 < SEQ / 64) {
            const size_t ko = (size_t)(g + 1) * 64 * DIM;
            const size_t vo = (size_t)(g + 1) * 64;
            const int nb = (g + 1) & 1;
            GLD16(kg + ko,                 kl0 + nb * 4096);
            GLD16(kg + ko + 32 * DIM,      kl0 + nb * 4096 + 2048);
            GLD16(vg + vo,                 vl0 + nb * 4096);
            GLD16(vg + vo + 32,            vl0 + nb * 4096 + 2048);
            mwpn = *(const uint2*)(mp + (size_t)(g + 1) * 2 * SEQ);
        }

        const int cb = g & 1;
        const unsigned short* Kt0 = &Kt[cb][0][0];
        const unsigned short* Kt1 = &Kt[cb][1][0];
        const unsigned short* Vs0 = &Vs[cb][0][0];
        const unsigned short* Vs1 = &Vs[cb][1][0];
        const unsigned int mq0 = mwp.x >> sh4;
        const unsigned int mq1 = mwp.y >> sh4;

        // sequential sub-tile chains: sc0 dies into pa0/pb0 before sc1 lives.
        // Scheduler still overlaps SM0 (VALU) with QK1 (MFMA) via dataflow.
        union { unsigned int u[4]; bf16x8 v; } pa0, pb0, pa1, pb1;
        {
            f32x16 sc0;
            TILE_QK(sc0, Kt0, mq0);
            TILE_SM(sc0, pa0, pb0);
        }
        {
            f32x16 sc1;
            TILE_QK(sc1, Kt1, mq1);
            TILE_SM(sc1, pa1, pb1);
        }
        TILE_PV(pa0, pb0, Vs0);
        TILE_PV(pa1, pb1, Vs1);

        mwp = mwpn;
    }

    // ---- epilogue: l(q) = lsum(lane) + lsum(lane^32); store O^T C-layout ----
    float lsum = (ls0 + ls1) + (ls2 + ls3);
    lsum += __shfl_xor(lsum, 32);
    const float inv = 1.f / lsum;
    float* orow = O + ((size_t)bh * SEQ + q0 + wave * 32 + q32) * DIM;
    #pragma unroll
    for (int dh = 0; dh < 2; ++dh) {
        #pragma unroll
        for (int r23 = 0; r23 < 4; ++r23) {
            float4 w;
            w.x = acc[dh][4 * r23 + 0] * inv;
            w.y = acc[dh][4 * r23 + 1] * inv;
            w.z = acc[dh][4 * r23 + 2] * inv;
            w.w = acc[dh][4 * r23 + 3] * inv;
            *(float4*)(orow + dh * 32 + r23 * 8 + h * 4) = w;
        }
    }
}

// ---------------- fallback (round-2 kernel, used if ws too small) ----------------
__global__ __launch_bounds__(256)
void attn_fallback_kernel(const float* __restrict__ Q,
                          const float* __restrict__ K,
                          const float* __restrict__ V,
                          const int* __restrict__ mask,
                          float* __restrict__ O)
{
    const int bh   = blockIdx.y;
    const int b    = bh >> 4;
    const int q0   = blockIdx.x * 64;
    const int tid  = threadIdx.x;
    const int wave = tid >> 6;
    const int lane = tid & 63;
    const int quad = lane >> 4;
    const int l16  = lane & 15;

    __shared__ __align__(16) unsigned short Klds[32][72];
    __shared__ __align__(16) unsigned short VT[64][40];
    __shared__ __align__(16) unsigned short Plds[4][16][40];

    const float* Qb = Q + (size_t)bh * SEQ * DIM;
    const float* Kb = K + (size_t)bh * SEQ * DIM;
    const float* Vb = V + (size_t)bh * SEQ * DIM;
    const int*   Mb = mask + (size_t)b * SEQ * SEQ;

    const int qrow_frag = q0 + wave * 16 + l16;
    bf16x8 qf0, qf1;
    {
        const float* qp = Qb + (size_t)qrow_frag * DIM + quad * 8;
        #pragma unroll
        for (int i = 0; i < 8; ++i) {
            qf0[i] = (short)f2bf(qp[i]);
            qf1[i] = (short)f2bf(qp[32 + i]);
        }
    }

    f32x4 acc[4];
    #pragma unroll
    for (int dg = 0; dg < 4; ++dg) acc[dg] = (f32x4){0.f, 0.f, 0.f, 0.f};
    float mrowv[4] = {-INFINITY, -INFINITY, -INFINITY, -INFINITY};
    float lrow[4] = {0.f, 0.f, 0.f, 0.f};

    const int skey = tid >> 3;
    const int sd0  = (tid & 7) * 8;
    const int vkey = tid & 31;
    const int vd0  = (tid >> 5) * 8;
    const int qrow_m = q0 + wave * 16 + quad * 4;

    for (int kb = 0; kb < SEQ; kb += 32) {
        __syncthreads();
        {
            const float* kp = Kb + (size_t)(kb + skey) * DIM + sd0;
            union { uint4 u4; unsigned short s[8]; } kw;
            #pragma unroll
            for (int i = 0; i < 8; ++i) kw.s[i] = f2bf(kp[i]);
            *(uint4*)&Klds[skey][sd0] = kw.u4;
        }
        {
            const float* vp = Vb + (size_t)(kb + vkey) * DIM + vd0;
            #pragma unroll
            for (int i = 0; i < 8; ++i) VT[vd0 + i][vkey] = f2bf(vp[i]);
        }
        __syncthreads();

        f32x4 scr[2];
        scr[0] = (f32x4){0.f, 0.f, 0.f, 0.f};
        scr[1] = (f32x4){0.f, 0.f, 0.f, 0.f};
        #pragma unroll
        for (int nt = 0; nt < 2; ++nt) {
            bf16x8 kf0 = *(const bf16x8*)&Klds[nt * 16 + l16][quad * 8];
            bf16x8 kf1 = *(const bf16x8*)&Klds[nt * 16 + l16][32 + quad * 8];
            scr[nt] = __builtin_amdgcn_mfma_f32_16x16x32_bf16(qf0, kf0, scr[nt], 0, 0, 0);
            scr[nt] = __builtin_amdgcn_mfma_f32_16x16x32_bf16(qf1, kf1, scr[nt], 0, 0, 0);
        }

        float x[2][4];
        #pragma unroll
        for (int nt = 0; nt < 2; ++nt)
            #pragma unroll
            for (int r = 0; r < 4; ++r) {
                int mv = Mb[(size_t)(qrow_m + r) * SEQ + kb + nt * 16 + l16];
                x[nt][r] = mv ? NEG_SCALED : scr[nt][r] * 0.125f;
            }

        float p[2][4];
        #pragma unroll
        for (int r = 0; r < 4; ++r) {
            float rm = fmaxf(x[0][r], x[1][r]);
            #pragma unroll
            for (int off = 1; off < 16; off <<= 1)
                rm = fmaxf(rm, __shfl_xor(rm, off, 16));
            float mn = fmaxf(mrowv[r], rm);
            float alpha = exp2f((mrowv[r] - mn) * LOG2E);
            mrowv[r] = mn;
            float p0 = exp2f((x[0][r] - mn) * LOG2E);
            float p1 = exp2f((x[1][r] - mn) * LOG2E);
            p[0][r] = p0; p[1][r] = p1;
            float rs = p0 + p1;
            #pragma unroll
            for (int off = 1; off < 16; off <<= 1)
                rs += __shfl_xor(rs, off, 16);
            lrow[r] = lrow[r] * alpha + rs;
            #pragma unroll
            for (int dg = 0; dg < 4; ++dg)
                acc[dg][r] *= alpha;
        }

        #pragma unroll
        for (int nt = 0; nt < 2; ++nt)
            #pragma unroll
            for (int r = 0; r < 4; ++r)
                Plds[wave][quad * 4 + r][nt * 16 + l16] = f2bf(p[nt][r]);

        bf16x8 pf = *(const bf16x8*)&Plds[wave][l16][quad * 8];

        #pragma unroll
        for (int dg = 0; dg < 4; ++dg) {
            bf16x8 vf = *(const bf16x8*)&VT[dg * 16 + l16][quad * 8];
            acc[dg] = __builtin_amdgcn_mfma_f32_16x16x32_bf16(pf, vf, acc[dg], 0, 0, 0);
        }
    }

    float* Ob = O + (size_t)bh * SEQ * DIM;
    #pragma unroll
    for (int r = 0; r < 4; ++r) {
        float inv = 1.f / lrow[r];
        #pragma unroll
        for (int dg = 0; dg < 4; ++dg)
            Ob[(size_t)(qrow_m + r) * DIM + dg * 16 + l16] = acc[dg][r] * inv;
    }
}

extern "C" void kernel_launch(void* const* d_in, const int* in_sizes, int n_in,
                              void* d_out, int out_size, void* d_ws, size_t ws_size,
                              hipStream_t stream) {
    const float* Q = (const float*)d_in[0];
    const float* K = (const float*)d_in[1];
    const float* V = (const float*)d_in[2];
    const int* mask = (const int*)d_in[3];
    float*        O = (float*)d_out;

    const size_t szK = (size_t)NBH * SEQ * DIM * 2;        // bf16 K
    const size_t szV = (size_t)NBH * SEQ * DIM * 2;        // bf16 Vt (tau key order)
    const size_t szM = (size_t)4 * SEQ * (SEQ / 32) * 4;   // packed transposed mask
    const size_t need = szK + szV + szM;

    if (ws_size >= need) {
        unsigned short* Kb = (unsigned short*)d_ws;
        unsigned short* Vt = (unsigned short*)((char*)d_ws + szK);
        unsigned int*  Mpt = (unsigned int*)((char*)d_ws + szK + szV);

        prep_all_kernel<<<dim3(7168), 256, 0, stream>>>(K, V, mask, Kb, Vt, Mpt);
        attn_main_kernel<<<dim3(SEQ / 128, NBH), 256, 0, stream>>>(Q, Kb, Vt, Mpt, O);
    } else {
        attn_fallback_kernel<<<dim3(SEQ / 64, NBH), 256, 0, stream>>>(Q, K, V, mask, O);
    }
}

// Round 4
// 267.319 us; speedup vs baseline: 1.0178x; 1.0178x over previous
//
#include <hip/hip_runtime.h>

// Attention B=4,H=16,S=2048,D=64. fp32 in/out, mask int32 (nonzero=masked).
// Round 11: fragment-blob K/V layout.
//  - prepass emits K/V in MFMA-fragment order: per 64-key group a 16KB blob;
//    every main-kernel ds_read_b128 is a contiguous 1KB wave read at
//    (shared base + imm offset) -> zero bank conflicts, zero addr VALU.
//  - main loop restored to round-9 interleaved order (QK0,QK1,SMPV0,SMPV1).
//  - mask stays paired (one dwordx2 per 64-key group).
// Blob layout per (bh, g): 8192 shorts:
//   K frag (sub,dc):    [sub*2048 + dc*512 + lane*8 + j] = K[g*64+sub*32+q32][dc*16+h*8+j]
//   V frag (sub,kk,dh): [4096 + sub*2048 + kk*1024 + dh*512 + lane*8 + j]
//                       = V^T_tau[d=dh*32+q32][u = g*64+sub*32+kk*16+h*8+j]
//   (lane = h*32+q32; tau = swap23 key order, verified round-7)
// MFMA 32x32x16 layouts (verified m74/m101):
//   A: lane holds A[m=lane&31][k=(lane>>5)*8+j]
//   B: lane holds B[k=(lane>>5)*8+j][n=lane&31]
//   C/D: lane holds D[row=(reg&3)+8*(reg>>2)+4*(lane>>5)][col=lane&31]

#define SEQ 2048
#define DIM 64
#define NBH 64
#define LOG2E 1.44269504088896340736f
#define SCL (0.125f * LOG2E)
#define NEG_SCALED -1.25e8f

typedef short bf16x8 __attribute__((ext_vector_type(8)));
typedef float f32x4 __attribute__((ext_vector_type(4)));
typedef float f32x16 __attribute__((ext_vector_type(16)));

static __device__ __forceinline__ unsigned short f2bf(float f) {
    unsigned int u = __float_as_uint(f);
    u += 0x7fffu + ((u >> 16) & 1u);   // RNE
    return (unsigned short)(u >> 16);
}

// async global->LDS, 16B per lane; LDS dest = wave-uniform base + lane*16
#define GLD16(gp, lp) __builtin_amdgcn_global_load_lds( \
    (const __attribute__((address_space(1))) unsigned int*)(gp), \
    (__attribute__((address_space(3))) unsigned int*)(lp), 16, 0, 0)

// ---------------- fused prepass ----------------
// blocks [0,1024): mask; [1024,3072): K-blob; [3072,5120): V-blob
__global__ __launch_bounds__(256)
void prep_all_kernel(const float* __restrict__ K, const float* __restrict__ V,
                     const int* __restrict__ M,
                     unsigned short* __restrict__ Fb, unsigned int* __restrict__ Mpt) {
    const int x = blockIdx.x;
    const int t = threadIdx.x;
    if (x < 1024) {
        // mask: int32 -> 1 bit/key, transposed+paired: Mpt[b][g64][q][e],
        // e = low/high 32-key half of the 64-key group (adjacent dwords).
        __shared__ unsigned int Wt[64][8];
        const int m  = x;                      // 0..1023
        const int b  = m >> 8;
        const int q0 = ((m >> 3) & 31) * 64;
        const int k0 = (m & 7) * 256;
        const int w  = t >> 6, l = t & 63;
        #pragma unroll 4
        for (int row = 0; row < 16; ++row) {
            const int q = q0 + w * 16 + row;
            int4 v4 = *(const int4*)(M + ((size_t)b * SEQ + q) * SEQ + k0 + l * 4);
            unsigned int nib = (unsigned int)(v4.x != 0) | ((unsigned int)(v4.y != 0) << 1)
                             | ((unsigned int)(v4.z != 0) << 2) | ((unsigned int)(v4.w != 0) << 3);
            unsigned int v = nib << (4 * (l & 7));
            v |= __shfl_xor(v, 1);
            v |= __shfl_xor(v, 2);
            v |= __shfl_xor(v, 4);
            if ((l & 7) == 0) Wt[w * 16 + row][l >> 3] = v;
        }
        __syncthreads();
        {
            const int q = t & 63, g0 = t >> 6;
            #pragma unroll
            for (int gg = 0; gg < 2; ++gg) {
                const int g = g0 + gg * 4;           // local 32-key tile 0..7
                const int G = (k0 >> 5) + g;         // global 32-key tile 0..63
                Mpt[(((size_t)b * 32 + (G >> 1)) * SEQ + q0 + q) * 2 + (G & 1)] = Wt[q][g];
            }
        }
    } else if (x < 3072) {
        // K-blob: one block per (bh, 64-key group); 512 fragment units of 16B.
        const int kb = x - 1024;
        const int bh = kb >> 5;
        const int g  = kb & 31;
        const float* Kg = K + ((size_t)bh * SEQ + g * 64) * DIM;
        unsigned short* Fo = Fb + (((size_t)bh * 32 + g) * 8192);
        #pragma unroll
        for (int i = 0; i < 2; ++i) {
            const int u   = i * 256 + t;          // 0..511
            const int sub = u >> 8;
            const int dc  = (u >> 6) & 3;
            const int ln  = u & 63;
            const int hh  = ln >> 5;
            const int q32 = ln & 31;
            const float* kp = Kg + (size_t)(sub * 32 + q32) * DIM + dc * 16 + hh * 8;
            float4 a = *(const float4*)kp;
            float4 b2 = *(const float4*)(kp + 4);
            union { uint4 q4; unsigned short s[8]; } w;
            w.s[0] = f2bf(a.x); w.s[1] = f2bf(a.y); w.s[2] = f2bf(a.z); w.s[3] = f2bf(a.w);
            w.s[4] = f2bf(b2.x); w.s[5] = f2bf(b2.y); w.s[6] = f2bf(b2.z); w.s[7] = f2bf(b2.w);
            *(uint4*)(Fo + (size_t)u * 8) = w.q4;
        }
    } else {
        // V-blob: one block per (bh, 64-key group). Phase 1: stage 64x64 tile
        // in tau key order (chunk-swizzled for conflict-free phase-2 reads).
        // Phase 2: emit V^T fragments in blob order.
        __shared__ __align__(16) unsigned short T[64 * 64];
        const int vb = x - 3072;
        const int bh = vb >> 5;
        const int g  = vb & 31;
        const int k0 = g * 64;
        {
            const float* Vb = V + ((size_t)bh * SEQ + k0) * DIM;
            #pragma unroll
            for (int j = 0; j < 4; ++j) {
                const int fi = (j * 256 + t) * 4;      // float idx in 64x64 tile
                const int kk = fi >> 6;                // physical key (local)
                const int d0 = fi & 63;                // multiple of 4
                float4 f = *(const float4*)(Vb + fi);
                const int u  = (kk & ~12) | ((kk & 4) << 1) | ((kk & 8) >> 1); // swap23
                const int cs = (d0 >> 4) ^ ((u >> 3) & 3);
                union { uint2 q; unsigned short s[4]; } w4;
                w4.s[0] = f2bf(f.x); w4.s[1] = f2bf(f.y);
                w4.s[2] = f2bf(f.z); w4.s[3] = f2bf(f.w);
                *(uint2*)&T[u * 64 + cs * 16 + (d0 & 15)] = w4.q;
            }
        }
        __syncthreads();
        {
            // thread t: d-pair (2p, 2p+1), unit (sub,kk,hh) = w2
            const int p   = t & 31;
            const int w2  = t >> 5;
            const int sub = w2 >> 2;
            const int kk  = (w2 >> 1) & 1;
            const int hh  = w2 & 1;
            const int dh  = p >> 4;
            const int q32a = (2 * p) & 31;
            const int ub  = sub * 32 + kk * 16 + hh * 8;
            const unsigned int* T32 = (const unsigned int*)T;
            union { uint4 q4; unsigned short s[8]; } o0, o1;
            #pragma unroll
            for (int j = 0; j < 8; ++j) {
                const int u  = ub + j;
                const int ch = (p >> 3) ^ ((u >> 3) & 3);
                unsigned int v = T32[u * 32 + ch * 8 + (p & 7)];
                o0.s[j] = (unsigned short)v;          // d = 2p
                o1.s[j] = (unsigned short)(v >> 16);  // d = 2p+1
            }
            unsigned short* dst = Fb + (((size_t)bh * 32 + g) * 8192) + 4096
                                + sub * 2048 + kk * 1024 + dh * 512 + hh * 256 + q32a * 8;
            *(uint4*)dst       = o0.q4;
            *(uint4*)(dst + 8) = o1.q4;
        }
    }
}

// ---------------- main ----------------

// QK^T (S^T) for one 32-key sub-tile: C-init from mask bits, 4 mfmas over d.
// kf reads: shared base Bl + compile-time imm -> conflict-free 1KB wave reads.
#define TILE_QK(sc, sub, mqv)                                                   \
    {                                                                           \
        _Pragma("unroll")                                                       \
        for (int r = 0; r < 16; ++r) {                                          \
            const int s_ = (r & 3) + 8 * (r >> 2);                              \
            sc[r] = __int_as_float(__builtin_amdgcn_sbfe(mqv, s_, 1) & 0xC2C80000u); \
        }                                                                       \
        __builtin_amdgcn_s_setprio(1);                                          \
        _Pragma("unroll")                                                       \
        for (int dc = 0; dc < 4; ++dc) {                                        \
            bf16x8 kf = *(const bf16x8*)(Bl + (sub) * 2048 + dc * 512);         \
            sc = __builtin_amdgcn_mfma_f32_32x32x16_bf16(kf, qf[dc], sc, 0, 0, 0); \
        }                                                                       \
        __builtin_amdgcn_s_setprio(0);                                          \
    }

// softmax (fixed-max, masked scores init'd to -100) + PV for one sub-tile.
#define TILE_SMPV(sc, sub)                                                      \
    {                                                                           \
        float pv_[16];                                                          \
        _Pragma("unroll")                                                       \
        for (int r = 0; r < 16; ++r) pv_[r] = __builtin_amdgcn_exp2f(sc[r]);    \
        _Pragma("unroll")                                                       \
        for (int r = 0; r < 16; r += 4) {                                       \
            ls0 += pv_[r + 0]; ls1 += pv_[r + 1];                               \
            ls2 += pv_[r + 2]; ls3 += pv_[r + 3];                               \
        }                                                                       \
        unsigned int pk_[8];                                                    \
        _Pragma("unroll")                                                       \
        for (int m = 0; m < 8; ++m)                                             \
            asm("v_cvt_pk_bf16_f32 %0, %1, %2"                                  \
                : "=v"(pk_[m]) : "v"(pv_[2 * m]), "v"(pv_[2 * m + 1]));         \
        __builtin_amdgcn_s_setprio(1);                                          \
        _Pragma("unroll")                                                       \
        for (int kk = 0; kk < 2; ++kk) {                                        \
            union { unsigned int u[4]; bf16x8 v; } fr;                          \
            fr.u[0] = pk_[4 * kk + 0]; fr.u[1] = pk_[4 * kk + 1];               \
            fr.u[2] = pk_[4 * kk + 2]; fr.u[3] = pk_[4 * kk + 3];               \
            _Pragma("unroll")                                                   \
            for (int dh = 0; dh < 2; ++dh) {                                    \
                bf16x8 vf = *(const bf16x8*)(Bl + 4096 + (sub) * 2048 + kk * 1024 + dh * 512); \
                acc[dh] = __builtin_amdgcn_mfma_f32_32x32x16_bf16(vf, fr.v, acc[dh], 0, 0, 0); \
            }                                                                   \
        }                                                                       \
        __builtin_amdgcn_s_setprio(0);                                          \
    }

__global__ __launch_bounds__(256, 4)
void attn_main_kernel(const float* __restrict__ Q,
                      const unsigned short* __restrict__ Fb,
                      const unsigned int* __restrict__ Mpt,
                      float* __restrict__ O)
{
    // XCD swizzle: n = linear block id (x fastest). XCD ~ n%8 (round-robin).
    // bh = ((n&7)<<3) | (n>>7): each XCD owns 8 consecutive bh (a single b),
    // all 16 q-blocks of each bh -> K/V/mask tiles stay L2-resident.
    const int n    = blockIdx.y * gridDim.x + blockIdx.x;   // [0,1024)
    const int bh   = ((n & 7) << 3) | (n >> 7);
    const int q0   = ((n >> 3) & 15) * 128;
    const int b    = bh >> 4;
    const int tid  = threadIdx.x;
    const int wave = tid >> 6;
    const int lane = tid & 63;
    const int h    = lane >> 5;    // k-half for 32x32 frags
    const int q32  = lane & 31;
    const int sh4  = 4 * h;

    __shared__ __align__(16) unsigned short Blob[2][8192];   // 16KB per buffer

    const unsigned short* Fbh = Fb + (size_t)bh * 32 * 8192;

    // ---- Q B-frags (Q^T): lane holds Q[q=q32][d = dc*16 + h*8 + j], scale folded ----
    bf16x8 qf[4];
    {
        const float* qp = Q + ((size_t)bh * SEQ + q0 + wave * 32 + q32) * DIM + h * 8;
        #pragma unroll
        for (int dc = 0; dc < 4; ++dc) {
            float4 xx = *(const float4*)(qp + dc * 16);
            float4 yy = *(const float4*)(qp + dc * 16 + 4);
            qf[dc][0] = (short)f2bf(xx.x * SCL); qf[dc][1] = (short)f2bf(xx.y * SCL);
            qf[dc][2] = (short)f2bf(xx.z * SCL); qf[dc][3] = (short)f2bf(xx.w * SCL);
            qf[dc][4] = (short)f2bf(yy.x * SCL); qf[dc][5] = (short)f2bf(yy.y * SCL);
            qf[dc][6] = (short)f2bf(yy.z * SCL); qf[dc][7] = (short)f2bf(yy.w * SCL);
        }
    }

    // ---- staging: linear copy, blob layout == LDS layout ----
    const unsigned short* fg = Fbh + wave * 2048 + lane * 8;   // + g*8192 + c*512

    // paired transposed mask: one dwordx2 per lane per 64-key group
    const unsigned int* mp = Mpt + ((size_t)b * 32 * SEQ + q0 + wave * 32 + q32) * 2;

    f32x16 acc[2];
    #pragma unroll
    for (int i = 0; i < 16; ++i) { acc[0][i] = 0.f; acc[1][i] = 0.f; }
    float ls0 = 0.f, ls1 = 0.f, ls2 = 0.f, ls3 = 0.f;

    // prologue: stage group 0
    #pragma unroll
    for (int c = 0; c < 4; ++c)
        GLD16(fg + c * 512, &Blob[0][wave * 2048 + c * 512]);
    uint2 mwp = *(const uint2*)mp;

    #pragma unroll 2
    for (int g = 0; g < SEQ / 64; ++g) {
        __syncthreads();   // drains vmcnt -> buf (g&1) ready for all waves;
                           // prefetch below is 1 group old at next drain

        uint2 mwpn = {0u, 0u};
        if (g + 1 < SEQ / 64) {
            const unsigned short* fgn = fg + (size_t)(g + 1) * 8192;
            const int nb = (g + 1) & 1;
            #pragma unroll
            for (int c = 0; c < 4; ++c)
                GLD16(fgn + c * 512, &Blob[nb][wave * 2048 + c * 512]);
            mwpn = *(const uint2*)(mp + (size_t)(g + 1) * 2 * SEQ);
        }

        const unsigned short* Bl = &Blob[g & 1][0] + lane * 8;
        const unsigned int mq0 = mwp.x >> sh4;
        const unsigned int mq1 = mwp.y >> sh4;

        // interleaved (round-9) order: SM0's VALU overlaps QK1's MFMA tail,
        // PV0's MFMAs overlap SM1's VALU.
        f32x16 sc0, sc1;
        TILE_QK(sc0, 0, mq0);
        TILE_QK(sc1, 1, mq1);
        TILE_SMPV(sc0, 0);
        TILE_SMPV(sc1, 1);

        mwp = mwpn;
    }

    // ---- epilogue: l(q) = lsum(lane) + lsum(lane^32); store O^T C-layout ----
    float lsum = (ls0 + ls1) + (ls2 + ls3);
    lsum += __shfl_xor(lsum, 32);
    const float inv = 1.f / lsum;
    float* orow = O + ((size_t)bh * SEQ + q0 + wave * 32 + q32) * DIM;
    #pragma unroll
    for (int dh = 0; dh < 2; ++dh) {
        #pragma unroll
        for (int r23 = 0; r23 < 4; ++r23) {
            float4 w;
            w.x = acc[dh][4 * r23 + 0] * inv;
            w.y = acc[dh][4 * r23 + 1] * inv;
            w.z = acc[dh][4 * r23 + 2] * inv;
            w.w = acc[dh][4 * r23 + 3] * inv;
            *(float4*)(orow + dh * 32 + r23 * 8 + h * 4) = w;
        }
    }
}

// ---------------- fallback (round-2 kernel, used if ws too small) ----------------
__global__ __launch_bounds__(256)
void attn_fallback_kernel(const float* __restrict__ Q,
                          const float* __restrict__ K,
                          const float* __restrict__ V,
                          const int* __restrict__ mask,
                          float* __restrict__ O)
{
    const int bh   = blockIdx.y;
    const int b    = bh >> 4;
    const int q0   = blockIdx.x * 64;
    const int tid  = threadIdx.x;
    const int wave = tid >> 6;
    const int lane = tid & 63;
    const int quad = lane >> 4;
    const int l16  = lane & 15;

    __shared__ __align__(16) unsigned short Klds[32][72];
    __shared__ __align__(16) unsigned short VT[64][40];
    __shared__ __align__(16) unsigned short Plds[4][16][40];

    const float* Qb = Q + (size_t)bh * SEQ * DIM;
    const float* Kb = K + (size_t)bh * SEQ * DIM;
    const float* Vb = V + (size_t)bh * SEQ * DIM;
    const int*   Mb = mask + (size_t)b * SEQ * SEQ;

    const int qrow_frag = q0 + wave * 16 + l16;
    bf16x8 qf0, qf1;
    {
        const float* qp = Qb + (size_t)qrow_frag * DIM + quad * 8;
        #pragma unroll
        for (int i = 0; i < 8; ++i) {
            qf0[i] = (short)f2bf(qp[i]);
            qf1[i] = (short)f2bf(qp[32 + i]);
        }
    }

    f32x4 acc[4];
    #pragma unroll
    for (int dg = 0; dg < 4; ++dg) acc[dg] = (f32x4){0.f, 0.f, 0.f, 0.f};
    float mrowv[4] = {-INFINITY, -INFINITY, -INFINITY, -INFINITY};
    float lrow[4] = {0.f, 0.f, 0.f, 0.f};

    const int skey = tid >> 3;
    const int sd0  = (tid & 7) * 8;
    const int vkey = tid & 31;
    const int vd0  = (tid >> 5) * 8;
    const int qrow_m = q0 + wave * 16 + quad * 4;

    for (int kb = 0; kb < SEQ; kb += 32) {
        __syncthreads();
        {
            const float* kp = Kb + (size_t)(kb + skey) * DIM + sd0;
            union { uint4 u4; unsigned short s[8]; } kw;
            #pragma unroll
            for (int i = 0; i < 8; ++i) kw.s[i] = f2bf(kp[i]);
            *(uint4*)&Klds[skey][sd0] = kw.u4;
        }
        {
            const float* vp = Vb + (size_t)(kb + vkey) * DIM + vd0;
            #pragma unroll
            for (int i = 0; i < 8; ++i) VT[vd0 + i][vkey] = f2bf(vp[i]);
        }
        __syncthreads();

        f32x4 scr[2];
        scr[0] = (f32x4){0.f, 0.f, 0.f, 0.f};
        scr[1] = (f32x4){0.f, 0.f, 0.f, 0.f};
        #pragma unroll
        for (int nt = 0; nt < 2; ++nt) {
            bf16x8 kf0 = *(const bf16x8*)&Klds[nt * 16 + l16][quad * 8];
            bf16x8 kf1 = *(const bf16x8*)&Klds[nt * 16 + l16][32 + quad * 8];
            scr[nt] = __builtin_amdgcn_mfma_f32_16x16x32_bf16(qf0, kf0, scr[nt], 0, 0, 0);
            scr[nt] = __builtin_amdgcn_mfma_f32_16x16x32_bf16(qf1, kf1, scr[nt], 0, 0, 0);
        }

        float x[2][4];
        #pragma unroll
        for (int nt = 0; nt < 2; ++nt)
            #pragma unroll
            for (int r = 0; r < 4; ++r) {
                int mv = Mb[(size_t)(qrow_m + r) * SEQ + kb + nt * 16 + l16];
                x[nt][r] = mv ? NEG_SCALED : scr[nt][r] * 0.125f;
            }

        float p[2][4];
        #pragma unroll
        for (int r = 0; r < 4; ++r) {
            float rm = fmaxf(x[0][r], x[1][r]);
            #pragma unroll
            for (int off = 1; off < 16; off <<= 1)
                rm = fmaxf(rm, __shfl_xor(rm, off, 16));
            float mn = fmaxf(mrowv[r], rm);
            float alpha = exp2f((mrowv[r] - mn) * LOG2E);
            mrowv[r] = mn;
            float p0 = exp2f((x[0][r] - mn) * LOG2E);
            float p1 = exp2f((x[1][r] - mn) * LOG2E);
            p[0][r] = p0; p[1][r] = p1;
            float rs = p0 + p1;
            #pragma unroll
            for (int off = 1; off < 16; off <<= 1)
                rs += __shfl_xor(rs, off, 16);
            lrow[r] = lrow[r] * alpha + rs;
            #pragma unroll
            for (int dg = 0; dg < 4; ++dg)
                acc[dg][r] *= alpha;
        }

        #pragma unroll
        for (int nt = 0; nt < 2; ++nt)
            #pragma unroll
            for (int r = 0; r < 4; ++r)
                Plds[wave][quad * 4 + r][nt * 16 + l16] = f2bf(p[nt][r]);

        bf16x8 pf = *(const bf16x8*)&Plds[wave][l16][quad * 8];

        #pragma unroll
        for (int dg = 0; dg < 4; ++dg) {
            bf16x8 vf = *(const bf16x8*)&VT[dg * 16 + l16][quad * 8];
            acc[dg] = __builtin_amdgcn_mfma_f32_16x16x32_bf16(pf, vf, acc[dg], 0, 0, 0);
        }
    }

    float* Ob = O + (size_t)bh * SEQ * DIM;
    #pragma unroll
    for (int r = 0; r < 4; ++r) {
        float inv = 1.f / lrow[r];
        #pragma unroll
        for (int dg = 0; dg < 4; ++dg)
            Ob[(size_t)(qrow_m + r) * DIM + dg * 16 + l16] = acc[dg][r] * inv;
    }
}

extern "C" void kernel_launch(void* const* d_in, const int* in_sizes, int n_in,
                              void* d_out, int out_size, void* d_ws, size_t ws_size,
                              hipStream_t stream) {
    const float* Q = (const float*)d_in[0];
    const float* K = (const float*)d_in[1];
    const float* V = (const float*)d_in[2];
    const int* mask = (const int*)d_in[3];
    float*        O = (float*)d_out;

    const size_t szF = (size_t)NBH * 32 * 8192 * 2;        // K+V fragment blobs
    const size_t szM = (size_t)4 * SEQ * (SEQ / 32) * 4;   // packed transposed mask
    const size_t need = szF + szM;

    if (ws_size >= need) {
        unsigned short* Fb = (unsigned short*)d_ws;
        unsigned int*  Mpt = (unsigned int*)((char*)d_ws + szF);

        prep_all_kernel<<<dim3(5120), 256, 0, stream>>>(K, V, mask, Fb, Mpt);
        attn_main_kernel<<<dim3(SEQ / 128, NBH), 256, 0, stream>>>(Q, Fb, Mpt, O);
    } else {
        attn_fallback_kernel<<<dim3(SEQ / 64, NBH), 256, 0, stream>>>(Q, K, V, mask, O);
    }
}